// Round 19
// baseline (115.981 us; speedup 1.0000x reference)
//
#include <hip/hip_runtime.h>
#include <hip/hip_bf16.h>
#include <cstdint>
#include <cstddef>

#define TOK 32768      // B*L
#define CCH 128        // H*NB channels (also DH)
#define DIN 1024       // D

typedef __attribute__((ext_vector_type(8))) short short8;
typedef __attribute__((ext_vector_type(4))) float f32x4;

#define LIST_CAP 65536u

static __device__ __forceinline__ uint16_t f2bf(float f) {
  __hip_bfloat16 h = __float2bfloat16(f);
  return __builtin_bit_cast(uint16_t, h);
}
static __device__ __forceinline__ float bf2f(uint16_t u) {
  __hip_bfloat16 h = __builtin_bit_cast(__hip_bfloat16, u);
  return __bfloat162float(h);
}
// split f32 into hi+lo bf16 (x ~= hi+lo, error ~2^-18 |x|)
static __device__ __forceinline__ void splitbf(float x, uint16_t& hi, uint16_t& lo) {
  hi = f2bf(x);
  lo = f2bf(x - bf2f(hi));
}
// native v_rcp_f32 (1 instr, rel err ~2^-22)
static __device__ __forceinline__ float fast_rcp(float x) {
  return __builtin_amdgcn_rcpf(x);
}
// fast tanh via native v_exp_f32 + v_rcp_f32: err ~1e-6 abs (z err ~3e-6)
static __device__ __forceinline__ float fast_tanh(float x) {
  const float ax = fabsf(x);
  const float e = __expf(-2.0f * ax);
  const float t = (1.0f - e) * fast_rcp(1.0f + e);
  return copysignf(t, x);
}
// fast erf: Abramowitz-Stegun 7.1.26 on __expf + v_rcp, max abs err ~1.5e-7.
static __device__ __forceinline__ float fast_erf(float x) {
  const float ax = fabsf(x);
  const float t = fast_rcp(fmaf(0.3275911f, ax, 1.0f));
  float p = fmaf(1.061405429f, t, -1.453152027f);
  p = fmaf(p, t, 1.421413741f);
  p = fmaf(p, t, -0.284496736f);
  p = fmaf(p, t, 0.254829592f);
  const float e = __expf(-ax * ax);
  const float r = 1.0f - p * t * e;
  return copysignf(r, x);
}

// ---------------- prep: pack weights ----------------
__global__ void prep_kernel(const float* __restrict__ r_w1, const float* __restrict__ r_w2,
                            const float* __restrict__ m_w1, const float* __restrict__ m_w2,
                            const float* __restrict__ logQ, const float* __restrict__ logRavg,
                            uint16_t* __restrict__ W1r, uint16_t* __restrict__ W2r,
                            uint16_t* __restrict__ W1mh, uint16_t* __restrict__ W1ml,
                            uint16_t* __restrict__ W2mh, uint16_t* __restrict__ W2ml,
                            float* __restrict__ PiArr, unsigned int* __restrict__ cnt)
{
  int idx = blockIdx.x * 256 + threadIdx.x;
  if (idx == 0) cnt[0] = 0;
  if (idx < 131072) {
    int e = idx;
    int j = e & 7, lane = (e >> 3) & 63, nt = (e >> 9) & 7, c = (e >> 12) & 1, kt = e >> 13;
    int k = kt * 64 + c * 32 + (lane >> 4) * 8 + j;
    int n = nt * 16 + (lane & 15);
    W1r[e] = f2bf(r_w1[k * 128 + n]);
  } else if (idx < 147456) {
    int e = idx - 131072;
    int j = e & 7, l = (e >> 3) & 63, c = (e >> 9) & 3, t = e >> 11;
    int k = c * 32 + (l >> 4) * 8 + j;
    int col = t * 16 + (l & 15);
    W2r[e] = f2bf(r_w2[k * 128 + col]);
  } else if (idx < 278528) {
    int e = idx - 147456;
    int j = e & 7, lane = (e >> 3) & 63, nt = (e >> 9) & 7, c = (e >> 12) & 1, kt = e >> 13;
    int k = kt * 64 + c * 32 + (lane >> 4) * 8 + j;
    int n = nt * 16 + (lane & 15);
    uint16_t h, l;
    splitbf(m_w1[k * 128 + n], h, l);
    W1mh[e] = h; W1ml[e] = l;
  } else if (idx < 294912) {
    int e = idx - 278528;
    int j = e & 7, l = (e >> 3) & 63, c = (e >> 9) & 3, t = e >> 11;
    int k = c * 32 + (l >> 4) * 8 + j;
    int col = t * 16 + (l & 15);
    uint16_t h, lo;
    splitbf(m_w2[k * 128 + col], h, lo);
    W2mh[e] = h; W2ml[e] = lo;
  } else if (idx < 295040) {
    int i = idx - 294912;
    float Q = expf(logQ[i]);
    float Rv = expf(logRavg[i]);
    PiArr[i] = 0.5f * (-Q + sqrtf(Q * Q + 4.0f * Q * Rv));
  }
}

// ---------------- fused_all: r-MLP (bf16 MFMA) + m-MLP (split-bf16 MFMA) + chunk aggregates ----------------
// FINAL (session lock, verified stable across R17/R18: 115.8 / 115.9us;
//  baseline was 157.0us; -26%).
//  Structure: tm2 x tn4 waves, t=2 channel slices (A-reads halved, conflicts
//  4.98M), B-frags register-pipelined across c-halves, 1-deep X prefetch,
//  compact swizzled LDS, dual 32-token aggregate emission (1024-chunk scan).
//  Wins: wave geometry (R1/R3/R7), wr-wrap epilogue + refine backstop (R2),
//  B-frag reg double-buffer (R4), fast transcendentals in throughput phases
//  (R14 tanh/exp -1.6us, R15 erf -2.6us, R16 rcp -1.4us).
//  K-loop scheduling plateau: 12 falsified levers (occupancy, conflicts,
//  barriers, LDS volume, prefetch depth, no-drain vmcnt [m230 regime gate],
//  phase-rails+setprio, block-occupancy) -- all within +-5%. Not a roofline
//  (no pipe >18%); escape requires full 8-phase co-design, which regressed
//  in both local probes (R6, R11). Tails total ~6us incl. 5 launches: done.
__global__ __launch_bounds__(512, 4) void fused_all(
    const float* __restrict__ X, const float* __restrict__ theta,
    const uint16_t* __restrict__ W1r, const uint16_t* __restrict__ W2r,
    const uint16_t* __restrict__ W1h, const uint16_t* __restrict__ W1l,
    const uint16_t* __restrict__ W2h, const uint16_t* __restrict__ W2l,
    const float* __restrict__ rB1, const float* __restrict__ rB2,
    const float* __restrict__ B1, const float* __restrict__ B2,
    const float* __restrict__ PiArr,
    float* __restrict__ out0, float* __restrict__ out1,
    float* __restrict__ out2, float* __restrict__ out3,
    float* __restrict__ AggA, float* __restrict__ AggU,
    unsigned int* __restrict__ cnt, unsigned int* __restrict__ list)
{
  union SM {
    struct { uint16_t Xh[2][64][64]; uint16_t Xl[2][64][64]; } s1;     // 32768 B
    struct { uint16_t Hh[64][128]; uint16_t Hl[64][128]; uint16_t Hr[64][128]; } s2; // 49152 B
    struct { float2 Agg[4][4][128]; } s3;   // 16384 B
  };
  __shared__ SM sm;

  const int tid = threadIdx.x;
  const int w = tid >> 6, lane = tid & 63;
  const int l15 = lane & 15, l4 = lane >> 4;
  const int tm = w >> 2, tn = w & 3;   // 2 token-groups x 4 channel-wave-groups
  const int tok0 = blockIdx.x * 64;

  f32x4 accm[2][2], accr[2][2];        // [mm][t]
#pragma unroll
  for (int mm = 0; mm < 2; ++mm)
#pragma unroll
    for (int t = 0; t < 2; ++t) { accm[mm][t] = 0.0f; accr[mm][t] = 0.0f; }

  const int rr = tid >> 4, cc = tid & 15;   // 32 row-slots x 16 col-chunks (x2 rows/thread)
  const int wofs = (cc * 8) ^ ((rr & 7) << 4);   // swizzled staging write offset
  float4 xa0, xa1;

  auto ldX = [&](int kt, float4& v0, float4& v1) {
    v0 = *reinterpret_cast<const float4*>(
        X + (size_t)(tok0 + rr) * DIN + kt * 64 + cc * 4);
    v1 = *reinterpret_cast<const float4*>(
        X + (size_t)(tok0 + rr + 32) * DIN + kt * 64 + cc * 4);
  };
  auto wrX = [&](int b, const float4& v0, const float4& v1) {
    ushort4 vh, vl;
    splitbf(v0.x, vh.x, vl.x);
    splitbf(v0.y, vh.y, vl.y);
    splitbf(v0.z, vh.z, vl.z);
    splitbf(v0.w, vh.w, vl.w);
    *reinterpret_cast<ushort4*>((char*)&sm.s1.Xh[b][rr][0] + wofs) = vh;
    *reinterpret_cast<ushort4*>((char*)&sm.s1.Xl[b][rr][0] + wofs) = vl;
    splitbf(v1.x, vh.x, vl.x);
    splitbf(v1.y, vh.y, vl.y);
    splitbf(v1.z, vh.z, vl.z);
    splitbf(v1.w, vh.w, vl.w);
    *reinterpret_cast<ushort4*>((char*)&sm.s1.Xh[b][rr + 32][0] + wofs) = vh;
    *reinterpret_cast<ushort4*>((char*)&sm.s1.Xl[b][rr + 32][0] + wofs) = vl;
  };
  // load W1 B-fragments for (kt, c): both t slices of this wave
  auto ldB = [&](int kt, int c, short8 (&h)[2], short8 (&l)[2], short8 (&r)[2]) {
#pragma unroll
    for (int t = 0; t < 2; ++t) {
      const size_t boff = (size_t)((((kt * 2 + c) * 8 + (tn * 2 + t)) * 64 + lane) * 8);
      h[t] = *reinterpret_cast<const short8*>(W1h + boff);
      l[t] = *reinterpret_cast<const short8*>(W1l + boff);
      r[t] = *reinterpret_cast<const short8*>(W1r + boff);
    }
  };
  // one c-half MFMA cluster: 4 A-reads feed 16 MFMAs
  auto cluster = [&](int buf, int c, short8 (&bh)[2], short8 (&bl)[2], short8 (&br)[2]) {
#pragma unroll
    for (int mm = 0; mm < 2; ++mm) {
      const int row = (tm * 2 + mm) * 16 + l15;
      const int ob = (c * 64 + l4 * 16) ^ ((l15 & 7) << 4);
      const short8 ah = *reinterpret_cast<const short8*>((const char*)&sm.s1.Xh[buf][row][0] + ob);
      const short8 al = *reinterpret_cast<const short8*>((const char*)&sm.s1.Xl[buf][row][0] + ob);
#pragma unroll
      for (int t = 0; t < 2; ++t) {
        accm[mm][t] = __builtin_amdgcn_mfma_f32_16x16x32_bf16(ah, bh[t], accm[mm][t], 0, 0, 0);
        accm[mm][t] = __builtin_amdgcn_mfma_f32_16x16x32_bf16(al, bh[t], accm[mm][t], 0, 0, 0);
        accm[mm][t] = __builtin_amdgcn_mfma_f32_16x16x32_bf16(ah, bl[t], accm[mm][t], 0, 0, 0);
        accr[mm][t] = __builtin_amdgcn_mfma_f32_16x16x32_bf16(ah, br[t], accr[mm][t], 0, 0, 0);
      }
    }
  };

  // prologue: stage kt0; B(0,c=0) into b0
  short8 b0h[2], b0l[2], b0r[2], b1h[2], b1l[2], b1r[2];
  ldX(0, xa0, xa1);
  wrX(0, xa0, xa1);
  ldB(0, 0, b0h, b0l, b0r);
  __syncthreads();

#pragma unroll
  for (int kt = 0; kt < 16; ++kt) {
    const int cur = kt & 1;
    if (kt < 15) ldX(kt + 1, xa0, xa1);     // 1-deep X prefetch
    ldB(kt, 1, b1h, b1l, b1r);              // c=1 frags; window = cluster c0
    cluster(cur, 0, b0h, b0l, b0r);
    if (kt < 15) ldB(kt + 1, 0, b0h, b0l, b0r);  // next-kt c=0; window = cluster c1 + barrier
    cluster(cur, 1, b1h, b1l, b1r);
    if (kt < 15) wrX(cur ^ 1, xa0, xa1);    // splitbf + ds_write after compute
    __syncthreads();
  }

  // bias + GELU -> H (m: hi/lo split, r: bf16)   [overlays s1 -> barrier above]
#pragma unroll
  for (int t = 0; t < 2; ++t) {
    const int n = (tn * 2 + t) * 16 + l15;
    const float b1m = B1[n];
    const float b1rr = rB1[n];
#pragma unroll
    for (int mm = 0; mm < 2; ++mm)
#pragma unroll
      for (int r = 0; r < 4; ++r) {
        const int row = (tm * 2 + mm) * 16 + l4 * 4 + r;
        const int ob = (2 * n) ^ ((row & 7) << 4);     // swizzled write offset
        const float v = accm[mm][t][r] + b1m;
        const float ev = fast_erf(v * 0.70710678118654752f);
        const float g = 0.5f * v * (ev + 1.0f);
        uint16_t gh, gl;
        splitbf(g, gh, gl);
        *reinterpret_cast<uint16_t*>((char*)&sm.s2.Hh[row][0] + ob) = gh;
        *reinterpret_cast<uint16_t*>((char*)&sm.s2.Hl[row][0] + ob) = gl;
        const float vr = accr[mm][t][r] + b1rr;
        const float gr = 0.5f * vr * (1.0f + fast_erf(vr * 0.70710678118654752f));
        *reinterpret_cast<uint16_t*>((char*)&sm.s2.Hr[row][0] + ob) = f2bf(gr);
      }
  }
  __syncthreads();

  // GEMM2 (K=128): m 3-term split + r single; W2 frags pipelined one c2 ahead
  f32x4 acc2m[2][2], acc2r[2][2];
#pragma unroll
  for (int mm = 0; mm < 2; ++mm)
#pragma unroll
    for (int t = 0; t < 2; ++t) { acc2m[mm][t] = 0.0f; acc2r[mm][t] = 0.0f; }

  short8 w2h[2][2], w2l[2][2], w2r[2][2];   // [c2&1][t]
#pragma unroll
  for (int t = 0; t < 2; ++t) {
    const size_t boff = (size_t)((((tn * 2 + t) * 4 + 0) * 64 + lane) * 8);
    w2h[0][t] = *reinterpret_cast<const short8*>(W2h + boff);
    w2l[0][t] = *reinterpret_cast<const short8*>(W2l + boff);
    w2r[0][t] = *reinterpret_cast<const short8*>(W2r + boff);
  }
#pragma unroll
  for (int c2 = 0; c2 < 4; ++c2) {
    const int cb = c2 & 1;
    if (c2 < 3) {
#pragma unroll
      for (int t = 0; t < 2; ++t) {
        const size_t boff = (size_t)((((tn * 2 + t) * 4 + (c2 + 1)) * 64 + lane) * 8);
        w2h[cb ^ 1][t] = *reinterpret_cast<const short8*>(W2h + boff);
        w2l[cb ^ 1][t] = *reinterpret_cast<const short8*>(W2l + boff);
        w2r[cb ^ 1][t] = *reinterpret_cast<const short8*>(W2r + boff);
      }
    }
#pragma unroll
    for (int mm = 0; mm < 2; ++mm) {
      const int row = (tm * 2 + mm) * 16 + l15;
      const int ob = (c2 * 64 + l4 * 16) ^ ((l15 & 7) << 4);
      const short8 ah = *reinterpret_cast<const short8*>((const char*)&sm.s2.Hh[row][0] + ob);
      const short8 al = *reinterpret_cast<const short8*>((const char*)&sm.s2.Hl[row][0] + ob);
      const short8 ar = *reinterpret_cast<const short8*>((const char*)&sm.s2.Hr[row][0] + ob);
#pragma unroll
      for (int t = 0; t < 2; ++t) {
        acc2m[mm][t] = __builtin_amdgcn_mfma_f32_16x16x32_bf16(ah, w2h[cb][t], acc2m[mm][t], 0, 0, 0);
        acc2m[mm][t] = __builtin_amdgcn_mfma_f32_16x16x32_bf16(al, w2h[cb][t], acc2m[mm][t], 0, 0, 0);
        acc2m[mm][t] = __builtin_amdgcn_mfma_f32_16x16x32_bf16(ah, w2l[cb][t], acc2m[mm][t], 0, 0, 0);
        acc2r[mm][t] = __builtin_amdgcn_mfma_f32_16x16x32_bf16(ar, w2r[cb][t], acc2r[mm][t], 0, 0, 0);
      }
    }
  }

  // epilogue r: Pi, K, R (overwrite acc2r with K for the aggregate phase)
#pragma unroll
  for (int t = 0; t < 2; ++t) {
    const int n = (tn * 2 + t) * 16 + l15;
    const float b2 = rB2[n];
    const float piv = PiArr[n];
#pragma unroll
    for (int mm = 0; mm < 2; ++mm)
#pragma unroll
      for (int r = 0; r < 4; ++r) {
        const int token = tok0 + (tm * 2 + mm) * 16 + l4 * 4 + r;
        float lr = acc2r[mm][t][r] + b2;
        lr = fminf(fmaxf(lr, -5.0f), 5.0f);
        const float R = __expf(lr);
        const float K = piv * fast_rcp(fmaxf(piv + R, 1e-8f));
        const size_t off = (size_t)token * CCH + n;
        out1[off] = piv;
        out2[off] = K;
        out3[off] = R;
        acc2r[mm][t][r] = K;
      }
  }

  // epilogue m: nu via direct 2*pi wrap (boundary cases flagged for exact refine)
#pragma unroll
  for (int t = 0; t < 2; ++t) {
    const int n = (tn * 2 + t) * 16 + l15;
    const float b2 = B2[n];
#pragma unroll
    for (int mm = 0; mm < 2; ++mm)
#pragma unroll
      for (int r = 0; r < 4; ++r) {
        const int token = tok0 + (tm * 2 + mm) * 16 + l4 * 4 + r;
        const float mz = acc2m[mm][t][r] + b2;
        const float z = 3.14159265358979323846f * fast_tanh(mz);
        const float d = z - theta[(size_t)token * CCH + n];
        const float wr = d - 6.2831853071795864769f * rintf(d * 0.15915494309189533577f);
        if (3.14159265358979323846f - fabsf(wr) < 3e-4f) {
          unsigned int p = atomicAdd(cnt, 1u);
          if (p < LIST_CAP) list[p] = (unsigned int)(token * CCH + n);
        }
        out0[(size_t)token * CCH + n] = wr;
        acc2m[mm][t][r] = wr;
      }
  }

  // chunk aggregates: per (ch, tokgrp, l4) 4-token r-chain, then ordered compose
  __syncthreads();   // all H reads done; safe to reuse union as s3
#pragma unroll
  for (int t = 0; t < 2; ++t) {
    const int n = (tn * 2 + t) * 16 + l15;
#pragma unroll
    for (int mm = 0; mm < 2; ++mm) {
      float A = 1.0f, U = 0.0f;
#pragma unroll
      for (int r = 0; r < 4; ++r) {
        const float k = acc2r[mm][t][r];
        const float v = acc2m[mm][t][r];
        const float a = 1.0f - k;
        A *= a;
        U = fmaf(a, U, k * v);
      }
      sm.s3.Agg[tm * 2 + mm][l4][n] = make_float2(A, U);
    }
  }
  __syncthreads();
  if (tid < 128) {
    const int ch = tid;
    // half 0: tokens 0-31 (groups 0..7, in order)
    float A = 1.0f, U = 0.0f;
#pragma unroll
    for (int g = 0; g < 8; ++g) {
      const float2 au = sm.s3.Agg[g >> 2][g & 3][ch];
      U = fmaf(au.x, U, au.y);
      A *= au.x;
    }
    AggA[(blockIdx.x * 2) * CCH + ch] = A;
    AggU[(blockIdx.x * 2) * CCH + ch] = U;
    // half 1: tokens 32-63 (groups 8..15, in order)
    float A1 = 1.0f, U1 = 0.0f;
#pragma unroll
    for (int g = 8; g < 16; ++g) {
      const float2 au = sm.s3.Agg[g >> 2][g & 3][ch];
      U1 = fmaf(au.x, U1, au.y);
      A1 *= au.x;
    }
    AggA[(blockIdx.x * 2 + 1) * CCH + ch] = A1;
    AggU[(blockIdx.x * 2 + 1) * CCH + ch] = U1;
  }
}

// ---------------- refine_nu: exact f32 sequential-chain recompute of flagged elems ----------------
__global__ __launch_bounds__(128) void refine_nu(
    const float* __restrict__ X, const float* __restrict__ theta,
    const float* __restrict__ W1, const float* __restrict__ B1,
    const float* __restrict__ W2, const float* __restrict__ B2,
    const unsigned int* __restrict__ cnt, const unsigned int* __restrict__ list,
    float* __restrict__ out0)
{
  __shared__ float h[128];
  const int j = threadIdx.x;
  const unsigned int n = min(cnt[0], LIST_CAP);
  for (unsigned int e = blockIdx.x; e < n; e += gridDim.x) {
    const unsigned int idx = list[e];
    const int tok = (int)(idx >> 7), ch = (int)(idx & 127);
    const float* xr = X + (size_t)tok * DIN;
    float acc = 0.0f;
    for (int k = 0; k < DIN; ++k)
      acc = fmaf(xr[k], W1[(size_t)k * CCH + j], acc);
    const float v = acc + B1[j];
    const float ev = erff(v / 1.41421356237309515f);
    h[j] = 0.5f * v * (ev + 1.0f);
    __syncthreads();
    if (j == 0) {
      float a2 = 0.0f;
      for (int k = 0; k < CCH; ++k)
        a2 = fmaf(h[k], W2[(size_t)k * CCH + ch], a2);
      const float mz = a2 + B2[ch];
      const float z = 3.14159265358979323846f * tanhf(mz);
      const float d = z - theta[(size_t)tok * CCH + ch];
      out0[(size_t)tok * CCH + ch] = atan2f(sinf(d), cosf(d));
    }
    __syncthreads();
  }
}

// ---------------- refine_agg: recompute 32-token chunk aggregates touched by refine_nu ----------------
__global__ __launch_bounds__(64) void refine_agg(
    const float* __restrict__ Kk, const float* __restrict__ nu,
    const unsigned int* __restrict__ cnt, const unsigned int* __restrict__ list,
    float* __restrict__ AggA, float* __restrict__ AggU)
{
  __shared__ float av[32], uv[32];
  const int i = threadIdx.x;
  const unsigned int n = min(cnt[0], LIST_CAP);
  for (unsigned int e = blockIdx.x; e < n; e += gridDim.x) {
    const unsigned int idx = list[e];
    const int ch = (int)(idx & 127);
    const int blk = (int)(idx >> 12);          // tok >> 5 (32-token chunk)
    if (i < 32) {
      const size_t off = (size_t)(blk * 32 + i) * CCH + ch;
      const float k = Kk[off];
      const float v = nu[off];
      av[i] = 1.0f - k;
      uv[i] = k * v;
    }
    __syncthreads();
    if (i == 0) {
      float A = 1.0f, U = 0.0f;
      for (int g = 0; g < 32; ++g) {
        U = fmaf(av[g], U, uv[g]);
        A *= av[g];
      }
      AggA[blk * CCH + ch] = A;
      AggU[blk * CCH + ch] = U;
    }
    __syncthreads();
  }
}

// ---------------- pass2: affine scan over 128 chunks per (b,ch) via pair-compose + 64-wide shfl ----------------
__global__ __launch_bounds__(256) void scan_pass2(
    const float* __restrict__ AggA, const float* __restrict__ AggU,
    float* __restrict__ Carry)
{
  const int wid = blockIdx.x * 4 + (threadIdx.x >> 6);  // 0..1023: (b, ch)
  const int b = wid >> 7, ch = wid & 127;
  const int g = threadIdx.x & 63;                        // pair index: chunks 2g, 2g+1
  const size_t i0 = (size_t)(b * 128 + 2 * g) * CCH + ch;
  const size_t i1 = (size_t)(b * 128 + 2 * g + 1) * CCH + ch;
  const float A0 = AggA[i0], U0 = AggU[i0];
  const float A1 = AggA[i1], U1 = AggU[i1];
  // pair composite (chunk 2g then chunk 2g+1)
  float A = A1 * A0;
  float U = fmaf(A1, U0, U1);
#pragma unroll
  for (int s = 1; s < 64; s <<= 1) {
    const float pA = __shfl_up(A, s);
    const float pU = __shfl_up(U, s);
    if (g >= s) {
      U = fmaf(A, pU, U);
      A = A * pA;
    }
  }
  float cU = __shfl_up(U, 1);       // exclusive pair-carry (composite of pairs 0..g-1)
  if (g == 0) cU = 0.0f;
  Carry[i0] = cU;                   // carry into chunk 2g
  Carry[i1] = fmaf(A0, cU, U0);     // carry into chunk 2g+1 (through chunk 2g)
}

// ---------------- pass3: apply (K/nu LDS-staged; 32-token serial chain from LDS) ----------------
__global__ __launch_bounds__(128) void scan_pass3(
    const float* __restrict__ Kk, const float* __restrict__ theta,
    const float* __restrict__ Carry, float* __restrict__ out0)
{
  __shared__ float kb[32 * CCH];
  __shared__ float vb[32 * CCH];
  const int c = threadIdx.x;
  const int blk = blockIdx.x;
  const size_t base = (size_t)blk * 32 * CCH;
  // parallel stage: 4096 floats per array = 1024 float4; 128 threads x 8 each
#pragma unroll
  for (int i = 0; i < 8; ++i) {
    const int e = i * 128 + c;
    reinterpret_cast<float4*>(kb)[e] = reinterpret_cast<const float4*>(Kk + base)[e];
    reinterpret_cast<float4*>(vb)[e] = reinterpret_cast<const float4*>(out0 + base)[e];
  }
  __syncthreads();
  float d = Carry[blk * CCH + c];
#pragma unroll 8
  for (int i = 0; i < 32; ++i) {
    const float k = kb[i * CCH + c];
    const float v = vb[i * CCH + c];
    d = fmaf(1.0f - k, d, k * v);
    const size_t off = base + (size_t)i * CCH + c;
    out0[off] = theta[off] + d;
  }
}

extern "C" void kernel_launch(void* const* d_in, const int* in_sizes, int n_in,
                              void* d_out, int out_size, void* d_ws, size_t ws_size,
                              hipStream_t stream) {
  const float* theta   = (const float*)d_in[0];
  const float* X       = (const float*)d_in[1];
  const float* logQ    = (const float*)d_in[2];
  const float* logRavg = (const float*)d_in[3];
  const float* r_w1    = (const float*)d_in[4];
  const float* r_b1    = (const float*)d_in[5];
  const float* r_w2    = (const float*)d_in[6];
  const float* r_b2    = (const float*)d_in[7];
  const float* m_w1    = (const float*)d_in[8];
  const float* m_b1    = (const float*)d_in[9];
  const float* m_w2    = (const float*)d_in[10];
  const float* m_b2    = (const float*)d_in[11];

  float* out0 = (float*)d_out;             // theta + d (nu scratch first)
  float* out1 = out0 + 4194304;            // Pi
  float* out2 = out0 + 2 * 4194304;        // K
  float* out3 = out0 + 3 * 4194304;        // R

  char* ws = (char*)d_ws;
  uint16_t* W1r  = (uint16_t*)(ws);                  // 262144 B
  uint16_t* W2r  = (uint16_t*)(ws + 262144);         // 32768 B
  float* PiArr   = (float*)(ws + 294912);            // 512 B
  float* AggA    = (float*)(ws + 295936);            // 524288 B (1024 chunks x 128 ch)
  float* AggU    = (float*)(ws + 820224);            // 524288 B
  float* Carry   = (float*)(ws + 1344512);           // 524288 B
  unsigned int* cnt  = (unsigned int*)(ws + 1868800);   // 256 B slot
  unsigned int* list = (unsigned int*)(ws + 1869056);   // 262144 B (LIST_CAP 65536)
  uint16_t* W1mh = (uint16_t*)(ws + 2131712);        // 262144 B
  uint16_t* W1ml = (uint16_t*)(ws + 2393856);        // 262144 B
  uint16_t* W2mh = (uint16_t*)(ws + 2656000);        // 32768 B
  uint16_t* W2ml = (uint16_t*)(ws + 2688768);        // 32768 B -> total 2721536

  prep_kernel<<<1153, 256, 0, stream>>>(r_w1, r_w2, m_w1, m_w2, logQ, logRavg,
                                        W1r, W2r, W1mh, W1ml, W2mh, W2ml,
                                        PiArr, cnt);
  fused_all<<<512, 512, 0, stream>>>(X, theta, W1r, W2r, W1mh, W1ml, W2mh, W2ml,
                                     r_b1, r_b2, m_b1, m_b2, PiArr,
                                     out0, out1, out2, out3, AggA, AggU, cnt, list);
  refine_nu<<<1024, 128, 0, stream>>>(X, theta, m_w1, m_b1, m_w2, m_b2,
                                      cnt, list, out0);
  refine_agg<<<1024, 64, 0, stream>>>(out2, out0, cnt, list, AggA, AggU);
  scan_pass2<<<256, 256, 0, stream>>>(AggA, AggU, Carry);
  scan_pass3<<<1024, 128, 0, stream>>>(out2, theta, Carry, out0);
}

// Round 20
// 115.503 us; speedup vs baseline: 1.0041x; 1.0041x over previous
//
#include <hip/hip_runtime.h>
#include <hip/hip_bf16.h>
#include <cstdint>
#include <cstddef>

#define TOK 32768      // B*L
#define CCH 128        // H*NB channels (also DH)
#define DIN 1024       // D

typedef __attribute__((ext_vector_type(8))) short short8;
typedef __attribute__((ext_vector_type(4))) float f32x4;

#define LIST_CAP 65536u

static __device__ __forceinline__ uint16_t f2bf(float f) {
  __hip_bfloat16 h = __float2bfloat16(f);
  return __builtin_bit_cast(uint16_t, h);
}
static __device__ __forceinline__ float bf2f(uint16_t u) {
  __hip_bfloat16 h = __builtin_bit_cast(__hip_bfloat16, u);
  return __bfloat162float(h);
}
// split f32 into hi+lo bf16 (x ~= hi+lo, error ~2^-18 |x|)
static __device__ __forceinline__ void splitbf(float x, uint16_t& hi, uint16_t& lo) {
  hi = f2bf(x);
  lo = f2bf(x - bf2f(hi));
}
// native v_rcp_f32 (1 instr, rel err ~2^-22)
static __device__ __forceinline__ float fast_rcp(float x) {
  return __builtin_amdgcn_rcpf(x);
}
// fast tanh via native v_exp_f32 + v_rcp_f32: err ~1e-6 abs (z err ~3e-6)
static __device__ __forceinline__ float fast_tanh(float x) {
  const float ax = fabsf(x);
  const float e = __expf(-2.0f * ax);
  const float t = (1.0f - e) * fast_rcp(1.0f + e);
  return copysignf(t, x);
}
// fast erf: Abramowitz-Stegun 7.1.26 on __expf + v_rcp, max abs err ~1.5e-7.
static __device__ __forceinline__ float fast_erf(float x) {
  const float ax = fabsf(x);
  const float t = fast_rcp(fmaf(0.3275911f, ax, 1.0f));
  float p = fmaf(1.061405429f, t, -1.453152027f);
  p = fmaf(p, t, 1.421413741f);
  p = fmaf(p, t, -0.284496736f);
  p = fmaf(p, t, 0.254829592f);
  const float e = __expf(-ax * ax);
  const float r = 1.0f - p * t * e;
  return copysignf(r, x);
}

// ---------------- prep: pack weights ----------------
__global__ void prep_kernel(const float* __restrict__ r_w1, const float* __restrict__ r_w2,
                            const float* __restrict__ m_w1, const float* __restrict__ m_w2,
                            const float* __restrict__ logQ, const float* __restrict__ logRavg,
                            uint16_t* __restrict__ W1r, uint16_t* __restrict__ W2r,
                            uint16_t* __restrict__ W1mh, uint16_t* __restrict__ W1ml,
                            uint16_t* __restrict__ W2mh, uint16_t* __restrict__ W2ml,
                            float* __restrict__ PiArr, unsigned int* __restrict__ cnt)
{
  int idx = blockIdx.x * 256 + threadIdx.x;
  if (idx == 0) cnt[0] = 0;
  if (idx < 131072) {
    int e = idx;
    int j = e & 7, lane = (e >> 3) & 63, nt = (e >> 9) & 7, c = (e >> 12) & 1, kt = e >> 13;
    int k = kt * 64 + c * 32 + (lane >> 4) * 8 + j;
    int n = nt * 16 + (lane & 15);
    W1r[e] = f2bf(r_w1[k * 128 + n]);
  } else if (idx < 147456) {
    int e = idx - 131072;
    int j = e & 7, l = (e >> 3) & 63, c = (e >> 9) & 3, t = e >> 11;
    int k = c * 32 + (l >> 4) * 8 + j;
    int col = t * 16 + (l & 15);
    W2r[e] = f2bf(r_w2[k * 128 + col]);
  } else if (idx < 278528) {
    int e = idx - 147456;
    int j = e & 7, lane = (e >> 3) & 63, nt = (e >> 9) & 7, c = (e >> 12) & 1, kt = e >> 13;
    int k = kt * 64 + c * 32 + (lane >> 4) * 8 + j;
    int n = nt * 16 + (lane & 15);
    uint16_t h, l;
    splitbf(m_w1[k * 128 + n], h, l);
    W1mh[e] = h; W1ml[e] = l;
  } else if (idx < 294912) {
    int e = idx - 278528;
    int j = e & 7, l = (e >> 3) & 63, c = (e >> 9) & 3, t = e >> 11;
    int k = c * 32 + (l >> 4) * 8 + j;
    int col = t * 16 + (l & 15);
    uint16_t h, lo;
    splitbf(m_w2[k * 128 + col], h, lo);
    W2mh[e] = h; W2ml[e] = lo;
  } else if (idx < 295040) {
    int i = idx - 294912;
    float Q = expf(logQ[i]);
    float Rv = expf(logRavg[i]);
    PiArr[i] = 0.5f * (-Q + sqrtf(Q * Q + 4.0f * Q * Rv));
  }
}

// ---------------- fused_all: r-MLP (bf16 MFMA) + m-MLP (split-bf16 MFMA) + chunk aggregates ----------------
// FINAL (session lock, verified stable across R17/R18/R19: 115.80/115.92/
//  115.98us; baseline was 157.0us; -26%).
//  Structure: tm2 x tn4 waves, t=2 channel slices (A-reads halved, conflicts
//  4.98M), B-frags register-pipelined across c-halves, 1-deep X prefetch,
//  compact swizzled LDS, dual 32-token aggregate emission (1024-chunk scan).
//  Wins: wave geometry (R1/R3/R7), wr-wrap epilogue + refine backstop (R2),
//  B-frag reg double-buffer (R4), fast transcendentals in throughput phases
//  (R14 tanh/exp -1.6us, R15 erf -2.6us, R16 rcp -1.4us).
//  K-loop scheduling plateau: 12 falsified levers (occupancy, conflicts,
//  barriers, LDS volume, prefetch depth, no-drain vmcnt [m230 regime gate],
//  phase-rails+setprio, block-occupancy) -- all within +-5%. Not a roofline
//  (no pipe >18%); escape requires full 8-phase co-design, which regressed
//  in both local probes (R6, R11). Tails total ~6us incl. 5 launches: done.
__global__ __launch_bounds__(512, 4) void fused_all(
    const float* __restrict__ X, const float* __restrict__ theta,
    const uint16_t* __restrict__ W1r, const uint16_t* __restrict__ W2r,
    const uint16_t* __restrict__ W1h, const uint16_t* __restrict__ W1l,
    const uint16_t* __restrict__ W2h, const uint16_t* __restrict__ W2l,
    const float* __restrict__ rB1, const float* __restrict__ rB2,
    const float* __restrict__ B1, const float* __restrict__ B2,
    const float* __restrict__ PiArr,
    float* __restrict__ out0, float* __restrict__ out1,
    float* __restrict__ out2, float* __restrict__ out3,
    float* __restrict__ AggA, float* __restrict__ AggU,
    unsigned int* __restrict__ cnt, unsigned int* __restrict__ list)
{
  union SM {
    struct { uint16_t Xh[2][64][64]; uint16_t Xl[2][64][64]; } s1;     // 32768 B
    struct { uint16_t Hh[64][128]; uint16_t Hl[64][128]; uint16_t Hr[64][128]; } s2; // 49152 B
    struct { float2 Agg[4][4][128]; } s3;   // 16384 B
  };
  __shared__ SM sm;

  const int tid = threadIdx.x;
  const int w = tid >> 6, lane = tid & 63;
  const int l15 = lane & 15, l4 = lane >> 4;
  const int tm = w >> 2, tn = w & 3;   // 2 token-groups x 4 channel-wave-groups
  const int tok0 = blockIdx.x * 64;

  f32x4 accm[2][2], accr[2][2];        // [mm][t]
#pragma unroll
  for (int mm = 0; mm < 2; ++mm)
#pragma unroll
    for (int t = 0; t < 2; ++t) { accm[mm][t] = 0.0f; accr[mm][t] = 0.0f; }

  const int rr = tid >> 4, cc = tid & 15;   // 32 row-slots x 16 col-chunks (x2 rows/thread)
  const int wofs = (cc * 8) ^ ((rr & 7) << 4);   // swizzled staging write offset
  float4 xa0, xa1;

  auto ldX = [&](int kt, float4& v0, float4& v1) {
    v0 = *reinterpret_cast<const float4*>(
        X + (size_t)(tok0 + rr) * DIN + kt * 64 + cc * 4);
    v1 = *reinterpret_cast<const float4*>(
        X + (size_t)(tok0 + rr + 32) * DIN + kt * 64 + cc * 4);
  };
  auto wrX = [&](int b, const float4& v0, const float4& v1) {
    ushort4 vh, vl;
    splitbf(v0.x, vh.x, vl.x);
    splitbf(v0.y, vh.y, vl.y);
    splitbf(v0.z, vh.z, vl.z);
    splitbf(v0.w, vh.w, vl.w);
    *reinterpret_cast<ushort4*>((char*)&sm.s1.Xh[b][rr][0] + wofs) = vh;
    *reinterpret_cast<ushort4*>((char*)&sm.s1.Xl[b][rr][0] + wofs) = vl;
    splitbf(v1.x, vh.x, vl.x);
    splitbf(v1.y, vh.y, vl.y);
    splitbf(v1.z, vh.z, vl.z);
    splitbf(v1.w, vh.w, vl.w);
    *reinterpret_cast<ushort4*>((char*)&sm.s1.Xh[b][rr + 32][0] + wofs) = vh;
    *reinterpret_cast<ushort4*>((char*)&sm.s1.Xl[b][rr + 32][0] + wofs) = vl;
  };
  // load W1 B-fragments for (kt, c): both t slices of this wave
  auto ldB = [&](int kt, int c, short8 (&h)[2], short8 (&l)[2], short8 (&r)[2]) {
#pragma unroll
    for (int t = 0; t < 2; ++t) {
      const size_t boff = (size_t)((((kt * 2 + c) * 8 + (tn * 2 + t)) * 64 + lane) * 8);
      h[t] = *reinterpret_cast<const short8*>(W1h + boff);
      l[t] = *reinterpret_cast<const short8*>(W1l + boff);
      r[t] = *reinterpret_cast<const short8*>(W1r + boff);
    }
  };
  // one c-half MFMA cluster: 4 A-reads feed 16 MFMAs
  auto cluster = [&](int buf, int c, short8 (&bh)[2], short8 (&bl)[2], short8 (&br)[2]) {
#pragma unroll
    for (int mm = 0; mm < 2; ++mm) {
      const int row = (tm * 2 + mm) * 16 + l15;
      const int ob = (c * 64 + l4 * 16) ^ ((l15 & 7) << 4);
      const short8 ah = *reinterpret_cast<const short8*>((const char*)&sm.s1.Xh[buf][row][0] + ob);
      const short8 al = *reinterpret_cast<const short8*>((const char*)&sm.s1.Xl[buf][row][0] + ob);
#pragma unroll
      for (int t = 0; t < 2; ++t) {
        accm[mm][t] = __builtin_amdgcn_mfma_f32_16x16x32_bf16(ah, bh[t], accm[mm][t], 0, 0, 0);
        accm[mm][t] = __builtin_amdgcn_mfma_f32_16x16x32_bf16(al, bh[t], accm[mm][t], 0, 0, 0);
        accm[mm][t] = __builtin_amdgcn_mfma_f32_16x16x32_bf16(ah, bl[t], accm[mm][t], 0, 0, 0);
        accr[mm][t] = __builtin_amdgcn_mfma_f32_16x16x32_bf16(ah, br[t], accr[mm][t], 0, 0, 0);
      }
    }
  };

  // prologue: stage kt0; B(0,c=0) into b0
  short8 b0h[2], b0l[2], b0r[2], b1h[2], b1l[2], b1r[2];
  ldX(0, xa0, xa1);
  wrX(0, xa0, xa1);
  ldB(0, 0, b0h, b0l, b0r);
  __syncthreads();

#pragma unroll
  for (int kt = 0; kt < 16; ++kt) {
    const int cur = kt & 1;
    if (kt < 15) ldX(kt + 1, xa0, xa1);     // 1-deep X prefetch
    ldB(kt, 1, b1h, b1l, b1r);              // c=1 frags; window = cluster c0
    cluster(cur, 0, b0h, b0l, b0r);
    if (kt < 15) ldB(kt + 1, 0, b0h, b0l, b0r);  // next-kt c=0; window = cluster c1 + barrier
    cluster(cur, 1, b1h, b1l, b1r);
    if (kt < 15) wrX(cur ^ 1, xa0, xa1);    // splitbf + ds_write after compute
    __syncthreads();
  }

  // bias + GELU -> H (m: hi/lo split, r: bf16)   [overlays s1 -> barrier above]
#pragma unroll
  for (int t = 0; t < 2; ++t) {
    const int n = (tn * 2 + t) * 16 + l15;
    const float b1m = B1[n];
    const float b1rr = rB1[n];
#pragma unroll
    for (int mm = 0; mm < 2; ++mm)
#pragma unroll
      for (int r = 0; r < 4; ++r) {
        const int row = (tm * 2 + mm) * 16 + l4 * 4 + r;
        const int ob = (2 * n) ^ ((row & 7) << 4);     // swizzled write offset
        const float v = accm[mm][t][r] + b1m;
        const float ev = fast_erf(v * 0.70710678118654752f);
        const float g = 0.5f * v * (ev + 1.0f);
        uint16_t gh, gl;
        splitbf(g, gh, gl);
        *reinterpret_cast<uint16_t*>((char*)&sm.s2.Hh[row][0] + ob) = gh;
        *reinterpret_cast<uint16_t*>((char*)&sm.s2.Hl[row][0] + ob) = gl;
        const float vr = accr[mm][t][r] + b1rr;
        const float gr = 0.5f * vr * (1.0f + fast_erf(vr * 0.70710678118654752f));
        *reinterpret_cast<uint16_t*>((char*)&sm.s2.Hr[row][0] + ob) = f2bf(gr);
      }
  }
  __syncthreads();

  // GEMM2 (K=128): m 3-term split + r single; W2 frags pipelined one c2 ahead
  f32x4 acc2m[2][2], acc2r[2][2];
#pragma unroll
  for (int mm = 0; mm < 2; ++mm)
#pragma unroll
    for (int t = 0; t < 2; ++t) { acc2m[mm][t] = 0.0f; acc2r[mm][t] = 0.0f; }

  short8 w2h[2][2], w2l[2][2], w2r[2][2];   // [c2&1][t]
#pragma unroll
  for (int t = 0; t < 2; ++t) {
    const size_t boff = (size_t)((((tn * 2 + t) * 4 + 0) * 64 + lane) * 8);
    w2h[0][t] = *reinterpret_cast<const short8*>(W2h + boff);
    w2l[0][t] = *reinterpret_cast<const short8*>(W2l + boff);
    w2r[0][t] = *reinterpret_cast<const short8*>(W2r + boff);
  }
#pragma unroll
  for (int c2 = 0; c2 < 4; ++c2) {
    const int cb = c2 & 1;
    if (c2 < 3) {
#pragma unroll
      for (int t = 0; t < 2; ++t) {
        const size_t boff = (size_t)((((tn * 2 + t) * 4 + (c2 + 1)) * 64 + lane) * 8);
        w2h[cb ^ 1][t] = *reinterpret_cast<const short8*>(W2h + boff);
        w2l[cb ^ 1][t] = *reinterpret_cast<const short8*>(W2l + boff);
        w2r[cb ^ 1][t] = *reinterpret_cast<const short8*>(W2r + boff);
      }
    }
#pragma unroll
    for (int mm = 0; mm < 2; ++mm) {
      const int row = (tm * 2 + mm) * 16 + l15;
      const int ob = (c2 * 64 + l4 * 16) ^ ((l15 & 7) << 4);
      const short8 ah = *reinterpret_cast<const short8*>((const char*)&sm.s2.Hh[row][0] + ob);
      const short8 al = *reinterpret_cast<const short8*>((const char*)&sm.s2.Hl[row][0] + ob);
      const short8 ar = *reinterpret_cast<const short8*>((const char*)&sm.s2.Hr[row][0] + ob);
#pragma unroll
      for (int t = 0; t < 2; ++t) {
        acc2m[mm][t] = __builtin_amdgcn_mfma_f32_16x16x32_bf16(ah, w2h[cb][t], acc2m[mm][t], 0, 0, 0);
        acc2m[mm][t] = __builtin_amdgcn_mfma_f32_16x16x32_bf16(al, w2h[cb][t], acc2m[mm][t], 0, 0, 0);
        acc2m[mm][t] = __builtin_amdgcn_mfma_f32_16x16x32_bf16(ah, w2l[cb][t], acc2m[mm][t], 0, 0, 0);
        acc2r[mm][t] = __builtin_amdgcn_mfma_f32_16x16x32_bf16(ar, w2r[cb][t], acc2r[mm][t], 0, 0, 0);
      }
    }
  }

  // epilogue r: Pi, K, R (overwrite acc2r with K for the aggregate phase)
#pragma unroll
  for (int t = 0; t < 2; ++t) {
    const int n = (tn * 2 + t) * 16 + l15;
    const float b2 = rB2[n];
    const float piv = PiArr[n];
#pragma unroll
    for (int mm = 0; mm < 2; ++mm)
#pragma unroll
      for (int r = 0; r < 4; ++r) {
        const int token = tok0 + (tm * 2 + mm) * 16 + l4 * 4 + r;
        float lr = acc2r[mm][t][r] + b2;
        lr = fminf(fmaxf(lr, -5.0f), 5.0f);
        const float R = __expf(lr);
        const float K = piv * fast_rcp(fmaxf(piv + R, 1e-8f));
        const size_t off = (size_t)token * CCH + n;
        out1[off] = piv;
        out2[off] = K;
        out3[off] = R;
        acc2r[mm][t][r] = K;
      }
  }

  // epilogue m: nu via direct 2*pi wrap (boundary cases flagged for exact refine)
#pragma unroll
  for (int t = 0; t < 2; ++t) {
    const int n = (tn * 2 + t) * 16 + l15;
    const float b2 = B2[n];
#pragma unroll
    for (int mm = 0; mm < 2; ++mm)
#pragma unroll
      for (int r = 0; r < 4; ++r) {
        const int token = tok0 + (tm * 2 + mm) * 16 + l4 * 4 + r;
        const float mz = acc2m[mm][t][r] + b2;
        const float z = 3.14159265358979323846f * fast_tanh(mz);
        const float d = z - theta[(size_t)token * CCH + n];
        const float wr = d - 6.2831853071795864769f * rintf(d * 0.15915494309189533577f);
        if (3.14159265358979323846f - fabsf(wr) < 3e-4f) {
          unsigned int p = atomicAdd(cnt, 1u);
          if (p < LIST_CAP) list[p] = (unsigned int)(token * CCH + n);
        }
        out0[(size_t)token * CCH + n] = wr;
        acc2m[mm][t][r] = wr;
      }
  }

  // chunk aggregates: per (ch, tokgrp, l4) 4-token r-chain, then ordered compose
  __syncthreads();   // all H reads done; safe to reuse union as s3
#pragma unroll
  for (int t = 0; t < 2; ++t) {
    const int n = (tn * 2 + t) * 16 + l15;
#pragma unroll
    for (int mm = 0; mm < 2; ++mm) {
      float A = 1.0f, U = 0.0f;
#pragma unroll
      for (int r = 0; r < 4; ++r) {
        const float k = acc2r[mm][t][r];
        const float v = acc2m[mm][t][r];
        const float a = 1.0f - k;
        A *= a;
        U = fmaf(a, U, k * v);
      }
      sm.s3.Agg[tm * 2 + mm][l4][n] = make_float2(A, U);
    }
  }
  __syncthreads();
  if (tid < 128) {
    const int ch = tid;
    // half 0: tokens 0-31 (groups 0..7, in order)
    float A = 1.0f, U = 0.0f;
#pragma unroll
    for (int g = 0; g < 8; ++g) {
      const float2 au = sm.s3.Agg[g >> 2][g & 3][ch];
      U = fmaf(au.x, U, au.y);
      A *= au.x;
    }
    AggA[(blockIdx.x * 2) * CCH + ch] = A;
    AggU[(blockIdx.x * 2) * CCH + ch] = U;
    // half 1: tokens 32-63 (groups 8..15, in order)
    float A1 = 1.0f, U1 = 0.0f;
#pragma unroll
    for (int g = 8; g < 16; ++g) {
      const float2 au = sm.s3.Agg[g >> 2][g & 3][ch];
      U1 = fmaf(au.x, U1, au.y);
      A1 *= au.x;
    }
    AggA[(blockIdx.x * 2 + 1) * CCH + ch] = A1;
    AggU[(blockIdx.x * 2 + 1) * CCH + ch] = U1;
  }
}

// ---------------- refine_nu: exact f32 sequential-chain recompute of flagged elems ----------------
__global__ __launch_bounds__(128) void refine_nu(
    const float* __restrict__ X, const float* __restrict__ theta,
    const float* __restrict__ W1, const float* __restrict__ B1,
    const float* __restrict__ W2, const float* __restrict__ B2,
    const unsigned int* __restrict__ cnt, const unsigned int* __restrict__ list,
    float* __restrict__ out0)
{
  __shared__ float h[128];
  const int j = threadIdx.x;
  const unsigned int n = min(cnt[0], LIST_CAP);
  for (unsigned int e = blockIdx.x; e < n; e += gridDim.x) {
    const unsigned int idx = list[e];
    const int tok = (int)(idx >> 7), ch = (int)(idx & 127);
    const float* xr = X + (size_t)tok * DIN;
    float acc = 0.0f;
    for (int k = 0; k < DIN; ++k)
      acc = fmaf(xr[k], W1[(size_t)k * CCH + j], acc);
    const float v = acc + B1[j];
    const float ev = erff(v / 1.41421356237309515f);
    h[j] = 0.5f * v * (ev + 1.0f);
    __syncthreads();
    if (j == 0) {
      float a2 = 0.0f;
      for (int k = 0; k < CCH; ++k)
        a2 = fmaf(h[k], W2[(size_t)k * CCH + ch], a2);
      const float mz = a2 + B2[ch];
      const float z = 3.14159265358979323846f * tanhf(mz);
      const float d = z - theta[(size_t)tok * CCH + ch];
      out0[(size_t)tok * CCH + ch] = atan2f(sinf(d), cosf(d));
    }
    __syncthreads();
  }
}

// ---------------- refine_agg: recompute 32-token chunk aggregates touched by refine_nu ----------------
__global__ __launch_bounds__(64) void refine_agg(
    const float* __restrict__ Kk, const float* __restrict__ nu,
    const unsigned int* __restrict__ cnt, const unsigned int* __restrict__ list,
    float* __restrict__ AggA, float* __restrict__ AggU)
{
  __shared__ float av[32], uv[32];
  const int i = threadIdx.x;
  const unsigned int n = min(cnt[0], LIST_CAP);
  for (unsigned int e = blockIdx.x; e < n; e += gridDim.x) {
    const unsigned int idx = list[e];
    const int ch = (int)(idx & 127);
    const int blk = (int)(idx >> 12);          // tok >> 5 (32-token chunk)
    if (i < 32) {
      const size_t off = (size_t)(blk * 32 + i) * CCH + ch;
      const float k = Kk[off];
      const float v = nu[off];
      av[i] = 1.0f - k;
      uv[i] = k * v;
    }
    __syncthreads();
    if (i == 0) {
      float A = 1.0f, U = 0.0f;
      for (int g = 0; g < 32; ++g) {
        U = fmaf(av[g], U, uv[g]);
        A *= av[g];
      }
      AggA[blk * CCH + ch] = A;
      AggU[blk * CCH + ch] = U;
    }
    __syncthreads();
  }
}

// ---------------- pass2: affine scan over 128 chunks per (b,ch) via pair-compose + 64-wide shfl ----------------
__global__ __launch_bounds__(256) void scan_pass2(
    const float* __restrict__ AggA, const float* __restrict__ AggU,
    float* __restrict__ Carry)
{
  const int wid = blockIdx.x * 4 + (threadIdx.x >> 6);  // 0..1023: (b, ch)
  const int b = wid >> 7, ch = wid & 127;
  const int g = threadIdx.x & 63;                        // pair index: chunks 2g, 2g+1
  const size_t i0 = (size_t)(b * 128 + 2 * g) * CCH + ch;
  const size_t i1 = (size_t)(b * 128 + 2 * g + 1) * CCH + ch;
  const float A0 = AggA[i0], U0 = AggU[i0];
  const float A1 = AggA[i1], U1 = AggU[i1];
  // pair composite (chunk 2g then chunk 2g+1)
  float A = A1 * A0;
  float U = fmaf(A1, U0, U1);
#pragma unroll
  for (int s = 1; s < 64; s <<= 1) {
    const float pA = __shfl_up(A, s);
    const float pU = __shfl_up(U, s);
    if (g >= s) {
      U = fmaf(A, pU, U);
      A = A * pA;
    }
  }
  float cU = __shfl_up(U, 1);       // exclusive pair-carry (composite of pairs 0..g-1)
  if (g == 0) cU = 0.0f;
  Carry[i0] = cU;                   // carry into chunk 2g
  Carry[i1] = fmaf(A0, cU, U0);     // carry into chunk 2g+1 (through chunk 2g)
}

// ---------------- pass3: apply (K/nu LDS-staged; 32-token serial chain from LDS) ----------------
__global__ __launch_bounds__(128) void scan_pass3(
    const float* __restrict__ Kk, const float* __restrict__ theta,
    const float* __restrict__ Carry, float* __restrict__ out0)
{
  __shared__ float kb[32 * CCH];
  __shared__ float vb[32 * CCH];
  const int c = threadIdx.x;
  const int blk = blockIdx.x;
  const size_t base = (size_t)blk * 32 * CCH;
  // parallel stage: 4096 floats per array = 1024 float4; 128 threads x 8 each
#pragma unroll
  for (int i = 0; i < 8; ++i) {
    const int e = i * 128 + c;
    reinterpret_cast<float4*>(kb)[e] = reinterpret_cast<const float4*>(Kk + base)[e];
    reinterpret_cast<float4*>(vb)[e] = reinterpret_cast<const float4*>(out0 + base)[e];
  }
  __syncthreads();
  float d = Carry[blk * CCH + c];
#pragma unroll 8
  for (int i = 0; i < 32; ++i) {
    const float k = kb[i * CCH + c];
    const float v = vb[i * CCH + c];
    d = fmaf(1.0f - k, d, k * v);
    const size_t off = base + (size_t)i * CCH + c;
    out0[off] = theta[off] + d;
  }
}

extern "C" void kernel_launch(void* const* d_in, const int* in_sizes, int n_in,
                              void* d_out, int out_size, void* d_ws, size_t ws_size,
                              hipStream_t stream) {
  const float* theta   = (const float*)d_in[0];
  const float* X       = (const float*)d_in[1];
  const float* logQ    = (const float*)d_in[2];
  const float* logRavg = (const float*)d_in[3];
  const float* r_w1    = (const float*)d_in[4];
  const float* r_b1    = (const float*)d_in[5];
  const float* r_w2    = (const float*)d_in[6];
  const float* r_b2    = (const float*)d_in[7];
  const float* m_w1    = (const float*)d_in[8];
  const float* m_b1    = (const float*)d_in[9];
  const float* m_w2    = (const float*)d_in[10];
  const float* m_b2    = (const float*)d_in[11];

  float* out0 = (float*)d_out;             // theta + d (nu scratch first)
  float* out1 = out0 + 4194304;            // Pi
  float* out2 = out0 + 2 * 4194304;        // K
  float* out3 = out0 + 3 * 4194304;        // R

  char* ws = (char*)d_ws;
  uint16_t* W1r  = (uint16_t*)(ws);                  // 262144 B
  uint16_t* W2r  = (uint16_t*)(ws + 262144);         // 32768 B
  float* PiArr   = (float*)(ws + 294912);            // 512 B
  float* AggA    = (float*)(ws + 295936);            // 524288 B (1024 chunks x 128 ch)
  float* AggU    = (float*)(ws + 820224);            // 524288 B
  float* Carry   = (float*)(ws + 1344512);           // 524288 B
  unsigned int* cnt  = (unsigned int*)(ws + 1868800);   // 256 B slot
  unsigned int* list = (unsigned int*)(ws + 1869056);   // 262144 B (LIST_CAP 65536)
  uint16_t* W1mh = (uint16_t*)(ws + 2131712);        // 262144 B
  uint16_t* W1ml = (uint16_t*)(ws + 2393856);        // 262144 B
  uint16_t* W2mh = (uint16_t*)(ws + 2656000);        // 32768 B
  uint16_t* W2ml = (uint16_t*)(ws + 2688768);        // 32768 B -> total 2721536

  prep_kernel<<<1153, 256, 0, stream>>>(r_w1, r_w2, m_w1, m_w2, logQ, logRavg,
                                        W1r, W2r, W1mh, W1ml, W2mh, W2ml,
                                        PiArr, cnt);
  fused_all<<<512, 512, 0, stream>>>(X, theta, W1r, W2r, W1mh, W1ml, W2mh, W2ml,
                                     r_b1, r_b2, m_b1, m_b2, PiArr,
                                     out0, out1, out2, out3, AggA, AggU, cnt, list);
  refine_nu<<<1024, 128, 0, stream>>>(X, theta, m_w1, m_b1, m_w2, m_b2,
                                      cnt, list, out0);
  refine_agg<<<1024, 64, 0, stream>>>(out2, out0, cnt, list, AggA, AggU);
  scan_pass2<<<256, 256, 0, stream>>>(AggA, AggU, Carry);
  scan_pass3<<<1024, 128, 0, stream>>>(out2, theta, Carry, out0);
}